// Round 21
// baseline (69.239 us; speedup 1.0000x reference)
//
#include <hip/hip_runtime.h>

typedef float f32x4 __attribute__((ext_vector_type(4)));
typedef __bf16 bf16x8 __attribute__((ext_vector_type(8)));
typedef unsigned short u16x8 __attribute__((ext_vector_type(8)));

__device__ __forceinline__ unsigned short f2bf(float f) {
  union { float f; unsigned u; } v; v.f = f;
  unsigned r = v.u + 0x7FFFu + ((v.u >> 16) & 1u);
  return (unsigned short)(r >> 16);
}

__device__ __forceinline__ float min3f(float a, float b, float c) {
  return fminf(fminf(a, b), c);
}
__device__ __forceinline__ float max3f(float a, float b, float c) {
  return fmaxf(fmaxf(a, b), c);
}
__device__ __forceinline__ float med3f(float a, float b, float c) {
  return __builtin_amdgcn_fmed3f(a, b, c);
}

// async global->LDS, 16B per lane, LDS dest = wave-uniform base + lane*16
__device__ __forceinline__ void gload_lds16(const void* g, void* l) {
  __builtin_amdgcn_global_load_lds(
      (const __attribute__((address_space(1))) void*)g,
      (__attribute__((address_space(3))) void*)l, 16, 0, 0);
}

// conv_w fp32 [256][256] -> bf16 in MFMA-fragment-linear order:
// wbf[((ks*16 + ob)*64 + lane)*8 + j] = bf16(W[ob*16 + (lane&15)][ks*32 + (lane>>4)*8 + j])
__global__ void wconv_k(const float* __restrict__ w, unsigned short* __restrict__ wbf) {
  int idx  = blockIdx.x * 256 + threadIdx.x;   // 0..8191
  int lane = idx & 63;
  int ob   = (idx >> 6) & 15;
  int ks   = idx >> 10;                        // 0..7
  int o = (ob << 4) + (lane & 15);
  int c = (ks << 5) + ((lane >> 4) << 3);
  const float* src = w + (o << 8) + c;
  f32x4 v0 = *(const f32x4*)src;
  f32x4 v1 = *(const f32x4*)(src + 4);
  u16x8 ov;
  ov[0] = f2bf(v0[0]); ov[1] = f2bf(v0[1]); ov[2] = f2bf(v0[2]); ov[3] = f2bf(v0[3]);
  ov[4] = f2bf(v1[0]); ov[5] = f2bf(v1[1]); ov[6] = f2bf(v1[2]); ov[7] = f2bf(v1[3]);
  *(u16x8*)(wbf + (idx << 3)) = ov;
}

// One block = (batch, row-QUAD): 256 px' (4 rows x 64) x 256 oc, 512 thr
// (8 waves). Halo amortization 1.5x (6 staged rows / 4 output rows) cuts
// the stage stream 262->196 MB vs R19. Wave (wm,wn) = (w>>2, w&3) owns
// M-half 128 px' x oc-quarter 64 -> acc = 128 regs/thread (R19 shape).
// R19's one-barrier step: stage(ks+1)->Xs[nxt] | wf | median+fold(Xs[cur])
// -> Bt[cur] | __syncthreads | pa(Bt[cur]) + MFMA. LDS 128 KB, 1 blk/CU.
__launch_bounds__(512, 1)
__global__ void fused_k(const float* __restrict__ x,
                        const unsigned short* __restrict__ wbf,
                        const float* __restrict__ bias,
                        float* __restrict__ out) {
  __shared__ float Xs[2][192][64];          // 96 KB: row = ci*6+dr, granule ^(ci&15)
  __shared__ unsigned short Bt[2][256][32]; // 32 KB: [buf][px'][c ^ ((s>>1)&3)<<3]

  const int t   = threadIdx.x;
  const int blk = blockIdx.x;
  const int swz = ((blk & 7) << 6) | (blk >> 3);   // XCD-bijective (512 = 8*64)
  const int b   = swz >> 4;
  const int r0  = (swz & 15) << 2;          // rows r0 .. r0+3
  const int lane = t & 63;
  const int w    = t >> 6;        // wave 0..7
  const int wm   = w >> 2;        // M-half
  const int wn   = w & 3;         // oc-quarter
  const int g    = lane >> 4;
  const int l15  = lane & 15;

  // median task: channel ci = t>>4 (0..31), strip s = lane&15 (4 px, 4 rows)
  const int ci  = t >> 4;
  const int s   = lane & 15;
  const int cw  = ci ^ (((s >> 1) & 3) << 3);   // matches pa reader XOR key
  const bool hasL = (s > 0), hasR = (s < 15);
  const bool zTop = (r0 == 0), zBot = (r0 == 60);

  const float* xb = x + ((size_t)b << 20);   // b * 256*64*64

  // staging: wave w covers Xs rows w*24 .. w*24+23 (channels 4w..4w+3, 6 rows)
  unsigned soff[6];
  #pragma unroll
  for (int p = 0; p < 6; ++p) {
    int gidx = w * 24 + (p << 2) + (lane >> 4);   // 0..191
    int cip  = (gidx * 171) >> 10;                // gidx / 6 (exact for < 192)
    int drp  = gidx - cip * 6;
    int gr   = r0 + drp - 1;
    gr = gr < 0 ? 0 : (gr > 63 ? 63 : gr);        // clamp; zeroed in VALU
    int bG   = (lane & 15) ^ (cip & 15);          // pre-swizzled px granule
    soff[p] = ((unsigned)cip << 14) + ((unsigned)gr << 8) + ((unsigned)bG << 4);
  }
  auto stage = [&](int step, int buf) {
    const unsigned kso = (unsigned)step << 19;    // step * 32ch * 16KB
    #pragma unroll
    for (int p = 0; p < 6; ++p)
      gload_lds16((const char*)xb + (soff[p] + kso), &Xs[buf][w * 24 + (p << 2)][0]);
  };

  f32x4 acc[8][4];   // [m: px' 16-blk within M-half][n: oc 16-blk within quarter]
  #pragma unroll
  for (int m = 0; m < 8; ++m)
    #pragma unroll
    for (int n = 0; n < 4; ++n)
      acc[m][n] = (f32x4){0.f, 0.f, 0.f, 0.f};

  stage(0, 0);
  __syncthreads();

  const int ri0 = ci * 6;
  const int gsw = s ^ (ci & 15);

  #pragma unroll
  for (int ks = 0; ks < 8; ++ks) {
    const int cur = ks & 1;

    // stage ks+1 into Xs[cur^1] (readers retired at barrier ks-1)
    if (ks < 7) stage(ks + 1, cur ^ 1);

    // W fragments: ob = wn*4 + n
    bf16x8 wfc[4];
    #pragma unroll
    for (int n = 0; n < 4; ++n) {
      const int fidx = (((ks << 4) + (wn << 2) + n) << 6) + lane;
      wfc[n] = __builtin_bit_cast(bf16x8, *(const u16x8*)(wbf + ((size_t)fidx << 3)));
    }

    // median source reads: 6 rows x 4 px from Xs[cur]
    f32x4 va[6];
    #pragma unroll
    for (int dr = 0; dr < 6; ++dr)
      va[dr] = *(const f32x4*)&Xs[cur][ri0 + dr][gsw << 2];
    float le[6], re[6];
    #pragma unroll
    for (int dr = 0; dr < 6; ++dr) {
      le[dr] = __shfl_up(va[dr][3], 1);
      re[dr] = __shfl_down(va[dr][0], 1);
    }
    if (zTop) { va[0] = (f32x4){0.f,0.f,0.f,0.f}; le[0] = 0.f; re[0] = 0.f; }
    if (zBot) { va[5] = (f32x4){0.f,0.f,0.f,0.f}; le[5] = 0.f; re[5] = 0.f; }

    // residual fold: oc block folds at step ks = wn*2 + (n>>1)
    if ((ks >> 1) == wn) {
      const int h = ks & 1;
      #pragma unroll
      for (int nn = 0; nn < 2; ++nn) {
        const int n    = (h << 1) + nn;
        const int cloc = (nn << 4) + l15;            // oc & 31
        #pragma unroll
        for (int m = 0; m < 8; ++m) {
          const int dr   = (wm << 1) + (m >> 2) + 1; // rr + 1
          const int gf   = ((m & 3) << 2) + g;       // px granule
          const int phys = (gf ^ (cloc & 15)) << 2;
          acc[m][n] += *(const f32x4*)&Xs[cur][cloc * 6 + dr][phys];
        }
      }
    }

    // medians: 4 output rows rr (staged rows rr..rr+2), 4 px each
    #pragma unroll
    for (int rr = 0; rr < 4; ++rr) {
      float c0[3], c5[3];
      #pragma unroll
      for (int d = 0; d < 3; ++d) {
        c0[d] = hasL ? le[rr + d] : 0.f;
        c5[d] = hasR ? re[rr + d] : 0.f;
      }
      float mn[6], md[6], mx[6];
      #pragma unroll
      for (int j = 0; j < 6; ++j) {
        float a0 = (j == 0) ? c0[0] : ((j == 5) ? c5[0] : va[rr][j - 1]);
        float a1 = (j == 0) ? c0[1] : ((j == 5) ? c5[1] : va[rr + 1][j - 1]);
        float a2 = (j == 0) ? c0[2] : ((j == 5) ? c5[2] : va[rr + 2][j - 1]);
        mn[j] = min3f(a0, a1, a2);
        md[j] = med3f(a0, a1, a2);
        mx[j] = max3f(a0, a1, a2);
      }
      #pragma unroll
      for (int i = 0; i < 4; ++i) {
        float t0 = max3f(mn[i], mn[i+1], mn[i+2]);
        float t1 = med3f(md[i], md[i+1], md[i+2]);
        float t2 = min3f(mx[i], mx[i+1], mx[i+2]);
        Bt[cur][(rr << 6) + (s << 2) + i][cw] = f2bf(med3f(t0, t1, t2));
      }
    }

    __syncthreads();   // Bt[cur] published; stage(ks+1) landed; Xs reads drained

    // pa fragments + MFMA: px' = wm*128 + m*16 + l15
    bf16x8 pa[8];
    #pragma unroll
    for (int m = 0; m < 8; ++m) {
      const int px = (wm << 7) + (m << 4) + l15;
      const int gc = (g ^ ((px >> 3) & 3)) << 3;
      pa[m] = __builtin_bit_cast(bf16x8, *(const u16x8*)&Bt[cur][px][gc]);
    }
    #pragma unroll
    for (int m = 0; m < 8; ++m)
      #pragma unroll
      for (int n = 0; n < 4; ++n)
        acc[m][n] = __builtin_amdgcn_mfma_f32_16x16x32_bf16(pa[m], wfc[n], acc[m][n], 0, 0, 0);
  }

  // epilogue (write-only): oc = wn*64+n*16+l15, row = r0+wm*2+(m>>2),
  // px = (m&3)*16 + g*4 + q
  #pragma unroll
  for (int n = 0; n < 4; ++n) {
    const int o  = (wn << 6) + (n << 4) + l15;
    const float bv = bias[o];
    #pragma unroll
    for (int m = 0; m < 8; ++m) {
      const size_t idx = ((((size_t)b << 8) + (size_t)o) << 12)
                       + ((size_t)(r0 + (wm << 1) + (m >> 2)) << 6)
                       + (size_t)(((m & 3) << 4) + (g << 2));
      f32x4 res;
      #pragma unroll
      for (int q = 0; q < 4; ++q) res[q] = acc[m][n][q] + bv;
      *(f32x4*)(out + idx) = res;
    }
  }
}

extern "C" void kernel_launch(void* const* d_in, const int* in_sizes, int n_in,
                              void* d_out, int out_size, void* d_ws, size_t ws_size,
                              hipStream_t stream) {
  const float* x  = (const float*)d_in[0];
  const float* cw = (const float*)d_in[1];
  const float* cb = (const float*)d_in[2];
  float* out = (float*)d_out;
  unsigned short* wbf = (unsigned short*)d_ws;   // 128 KB fragment-linear W

  hipLaunchKernelGGL(wconv_k, dim3(32), dim3(256), 0, stream, cw, wbf);
  hipLaunchKernelGGL(fused_k, dim3(512), dim3(512), 0, stream, x, wbf, cb, out);
}